// Round 6
// baseline (392.381 us; speedup 1.0000x reference)
//
#include <hip/hip_runtime.h>

// FeatureSelfAttention: B=32, T=2048, F=64
// out[b,t,i]    = x[b,t,i] + gamma[i] * mixed[b,t,i]
// attn[b,t,i,j] = softmax_j( q_i * k_j / 8 ),  q = x Wq^T, k = x Wk^T.
//
// R6: two-kernel split. Kernel A computes q,k per position (f16 dot2 matvec)
// into d_ws. Kernel B writes the 1.07 GB attn buffer as a grid-stride DENSE
// ascending sweep of 1 KB chunks -- byte-for-byte the access pattern of
// __amd_rocclr_fillBufferAligned, which achieves 6.5 TB/s on this buffer,
// vs ~4.9 TB/s for all our per-position round-robin variants. Theory: 4096
// scattered 16 KB write streams thrash HBM rows; one dense sliding window
// does not. A chunk = 4 complete softmax rows: B recomputes exp2 from
// k/qs (L2-hot, 16x reuse), row-sums via shfl_xor in 16-lane groups
// (softmax self-consistent by construction), and computes `out` on the side.
// No max-subtraction: |qs*k| <= ~1.9 provably. Fallback to single-kernel R2
// if ws_size < 32 MB.

#define LOG2E 1.4426950408889634f

constexpr int F = 64;

typedef _Float16 h2v __attribute__((ext_vector_type(2)));

#if defined(__has_builtin)
#if __has_builtin(__builtin_amdgcn_fdot2)
#define HAVE_FDOT2 1
#endif
#endif

static __device__ __forceinline__ float fdot2(h2v a, h2v b, float c) {
#ifdef HAVE_FDOT2
    return __builtin_amdgcn_fdot2(a, b, c, false);
#else
    return c + (float)a[0] * (float)b[0] + (float)a[1] * (float)b[1];
#endif
}

// ---------------------------------------------------------------------------
// Kernel A: per-position matvec. k[t][i] = x[t]·Wk_row_i, qs[t][i] scaled q.
// ---------------------------------------------------------------------------
__global__ __launch_bounds__(256, 4)
void fsattn_qk(const float* __restrict__ X,
               const float* __restrict__ Wq,
               const float* __restrict__ Wk,
               float* __restrict__ kbuf,
               float* __restrict__ qsbuf,
               int BT)
{
    const int lane = threadIdx.x & 63;
    const int wid  = threadIdx.x >> 6;
    const int gw   = (blockIdx.x << 2) + wid;
    const int nw   = gridDim.x << 2;

    __shared__ _Float16 xh_lds[4][F];

    h2v wq2[32], wk2[32];
#pragma unroll
    for (int p = 0; p < 32; ++p) {
        const float2 a = reinterpret_cast<const float2*>(Wq + lane * F)[p];
        const float2 b = reinterpret_cast<const float2*>(Wk + lane * F)[p];
        h2v ha; ha[0] = (_Float16)a.x; ha[1] = (_Float16)a.y;
        h2v hb; hb[0] = (_Float16)b.x; hb[1] = (_Float16)b.y;
        wq2[p] = ha; wk2[p] = hb;
    }

    for (int t = gw; t < BT; t += nw) {
        const float xv = X[(size_t)t * F + lane];
        xh_lds[wid][lane] = (_Float16)xv;
        __builtin_amdgcn_wave_barrier();

        float q = 0.f, k = 0.f;
        const h2v* xh = reinterpret_cast<const h2v*>(xh_lds[wid]);
#pragma unroll
        for (int p = 0; p < 32; ++p) {
            const h2v xp = xh[p];
            q = fdot2(wq2[p], xp, q);
            k = fdot2(wk2[p], xp, k);
        }
        __builtin_amdgcn_wave_barrier();

        kbuf [(size_t)t * F + lane] = k;
        qsbuf[(size_t)t * F + lane] = q * (0.125f * LOG2E);
    }
}

// ---------------------------------------------------------------------------
// Kernel B: dense ascending 1 KB-chunk sweep writer (fill-like pattern).
// chunk c -> position t = c>>4, rows 4*(c&15)..+3. 16-lane group per row.
// ---------------------------------------------------------------------------
__global__ __launch_bounds__(256, 8)
void fsattn_wr(const float* __restrict__ X,
               const float* __restrict__ kbuf,
               const float* __restrict__ qsbuf,
               const float* __restrict__ gamma,
               float* __restrict__ out,
               float* __restrict__ attn,
               long NC)
{
    const int lane = threadIdx.x & 63;
    const int c16  = lane & 15;
    const int sub  = lane >> 4;
    const long gwv = (long)((blockIdx.x * blockDim.x + threadIdx.x) >> 6);
    const long nwv = (long)((gridDim.x * blockDim.x) >> 6);

    long c = gwv;
    if (c >= NC) return;

    // prefetch for first chunk
    int t   = (int)(c >> 4);
    int row = ((int)(c & 15)) * 4 + sub;
    float4 kc  = reinterpret_cast<const float4*>(kbuf + (size_t)t * F)[c16];
    float4 x4  = reinterpret_cast<const float4*>(X    + (size_t)t * F)[c16];
    float  qsr = qsbuf[(size_t)t * F + row];
    float  xr  = X    [(size_t)t * F + row];
    float  gr  = gamma[row];

    for (; c < NC; c += nwv) {
        const long cn = c + nwv;
        const float4 kcc = kc;  const float4 x4c = x4;
        const float  qsc = qsr; const float  xrc = xr; const float grc = gr;
        const int    tc  = t;   const int    rowc = row;

        // issue next chunk's loads before this chunk's stores (vmcnt order)
        if (cn < NC) {
            t   = (int)(cn >> 4);
            row = ((int)(cn & 15)) * 4 + sub;
            kc  = reinterpret_cast<const float4*>(kbuf + (size_t)t * F)[c16];
            x4  = reinterpret_cast<const float4*>(X    + (size_t)t * F)[c16];
            qsr = qsbuf[(size_t)t * F + row];
            xr  = X    [(size_t)t * F + row];
            gr  = gamma[row];
        }

        // exp2 for this group's row, 4 columns per lane
        const float e0 = __builtin_amdgcn_exp2f(qsc * kcc.x);
        const float e1 = __builtin_amdgcn_exp2f(qsc * kcc.y);
        const float e2 = __builtin_amdgcn_exp2f(qsc * kcc.z);
        const float e3 = __builtin_amdgcn_exp2f(qsc * kcc.w);

        float ps = (e0 + e1) + (e2 + e3);
        float pm = __builtin_fmaf(e0, x4c.x, __builtin_fmaf(e1, x4c.y,
                   __builtin_fmaf(e2, x4c.z, e3 * x4c.w)));
        // 16-lane row reduction (lane = sub*16 + c16; xor stays in group)
#pragma unroll
        for (int s = 1; s < 16; s <<= 1) {
            ps += __shfl_xor(ps, s, 64);
            pm += __shfl_xor(pm, s, 64);
        }
        const float inv = __builtin_amdgcn_rcpf(ps);

        float4 w;
        w.x = e0 * inv; w.y = e1 * inv; w.z = e2 * inv; w.w = e3 * inv;
        reinterpret_cast<float4*>(attn + (size_t)c * 256)[lane] = w;

        if (c16 == 0)
            out[(size_t)tc * F + rowc] = xrc + grc * (pm * inv);
    }
}

// ---------------------------------------------------------------------------
// Fallback single kernel (R2, proven 227 us) if ws is too small.
// ---------------------------------------------------------------------------
__global__ __launch_bounds__(256, 4)
void fsattn_mono(const float* __restrict__ X,
                 const float* __restrict__ Wq,
                 const float* __restrict__ Wk,
                 const float* __restrict__ gamma,
                 float* __restrict__ out,
                 float* __restrict__ attn,
                 int BT)
{
    const int lane = threadIdx.x & 63;
    const int wid  = threadIdx.x >> 6;
    const int gw   = (blockIdx.x << 2) + wid;
    const int nw   = gridDim.x << 2;

    __shared__ float    x_lds[4][F];
    __shared__ float    k_lds[4][F];
    __shared__ _Float16 xh_lds[4][F];
    __shared__ float2   ql_lds[4][F];

    h2v wq2[32], wk2[32];
#pragma unroll
    for (int p = 0; p < 32; ++p) {
        const float2 a = reinterpret_cast<const float2*>(Wq + lane * F)[p];
        const float2 b = reinterpret_cast<const float2*>(Wk + lane * F)[p];
        h2v ha; ha[0] = (_Float16)a.x; ha[1] = (_Float16)a.y;
        h2v hb; hb[0] = (_Float16)b.x; hb[1] = (_Float16)b.y;
        wq2[p] = ha; wk2[p] = hb;
    }
    const float g = gamma[lane];

    for (int t = gw; t < BT; t += nw) {
        const float xv = X[(size_t)t * F + lane];
        x_lds[wid][lane]  = xv;
        xh_lds[wid][lane] = (_Float16)xv;
        __builtin_amdgcn_wave_barrier();

        float q = 0.f, k = 0.f;
        const h2v* xh = reinterpret_cast<const h2v*>(xh_lds[wid]);
#pragma unroll
        for (int p = 0; p < 32; ++p) {
            const h2v xp = xh[p];
            q = fdot2(wq2[p], xp, q);
            k = fdot2(wk2[p], xp, k);
        }
        const float qs = q * (0.125f * LOG2E);
        k_lds[wid][lane] = k;
        __builtin_amdgcn_wave_barrier();

        float sum0 = 0.f, sum1 = 0.f, mix0 = 0.f, mix1 = 0.f;
#pragma unroll
        for (int j = 0; j < 16; ++j) {
            const float4 k4 = reinterpret_cast<const float4*>(k_lds[wid])[j];
            const float4 x4 = reinterpret_cast<const float4*>(x_lds[wid])[j];
            const float e0 = __builtin_amdgcn_exp2f(qs * k4.x);
            const float e1 = __builtin_amdgcn_exp2f(qs * k4.y);
            const float e2 = __builtin_amdgcn_exp2f(qs * k4.z);
            const float e3 = __builtin_amdgcn_exp2f(qs * k4.w);
            sum0 += e0 + e1;
            sum1 += e2 + e3;
            mix0 = __builtin_fmaf(e0, x4.x, __builtin_fmaf(e1, x4.y, mix0));
            mix1 = __builtin_fmaf(e2, x4.z, __builtin_fmaf(e3, x4.w, mix1));
        }
        const float sum = sum0 + sum1;
        const float inv = __builtin_amdgcn_rcpf(sum);
        const float li  = -__builtin_amdgcn_logf(sum);
        float2 ql; ql.x = qs; ql.y = li;
        ql_lds[wid][lane] = ql;
        __builtin_amdgcn_wave_barrier();

        out[(size_t)t * F + lane] = xv + g * ((mix0 + mix1) * inv);

        float* ap = attn + (size_t)t * (F * F);
        const int sub = lane >> 4;
        const int c16 = lane & 15;
        const float4 kc = reinterpret_cast<const float4*>(k_lds[wid])[c16];
#pragma unroll
        for (int i0 = 0; i0 < F; i0 += 4) {
            const int row = i0 + sub;
            const float2 qr = ql_lds[wid][row];
            float4 w;
            w.x = __builtin_amdgcn_exp2f(__builtin_fmaf(qr.x, kc.x, qr.y));
            w.y = __builtin_amdgcn_exp2f(__builtin_fmaf(qr.x, kc.y, qr.y));
            w.z = __builtin_amdgcn_exp2f(__builtin_fmaf(qr.x, kc.z, qr.y));
            w.w = __builtin_amdgcn_exp2f(__builtin_fmaf(qr.x, kc.w, qr.y));
            reinterpret_cast<float4*>(ap + (size_t)row * F)[c16] = w;
        }
    }
}

extern "C" void kernel_launch(void* const* d_in, const int* in_sizes, int n_in,
                              void* d_out, int out_size, void* d_ws, size_t ws_size,
                              hipStream_t stream) {
    const float* X     = (const float*)d_in[0];
    const float* Wq    = (const float*)d_in[1];
    const float* Wk    = (const float*)d_in[2];
    const float* gamma = (const float*)d_in[3];

    const int BT = in_sizes[0] / F;              // 65536 positions
    float* out  = (float*)d_out;                 // (B,T,F) first
    float* attn = out + (size_t)BT * F;          // then (B,T,F,F)

    const size_t need = 2ull * (size_t)BT * F * sizeof(float);  // 32 MB
    if (ws_size >= need) {
        float* kbuf  = (float*)d_ws;
        float* qsbuf = kbuf + (size_t)BT * F;
        hipLaunchKernelGGL(fsattn_qk, dim3(1024), dim3(256), 0, stream,
                           X, Wq, Wk, kbuf, qsbuf, BT);
        const long NC = (long)BT * 16;           // 1 KB chunks
        hipLaunchKernelGGL(fsattn_wr, dim3(2048), dim3(256), 0, stream,
                           X, kbuf, qsbuf, gamma, out, attn, NC);
    } else {
        hipLaunchKernelGGL(fsattn_mono, dim3(1024), dim3(256), 0, stream,
                           X, Wq, Wk, gamma, out, attn, BT);
    }
}

// Round 8
// 346.331 us; speedup vs baseline: 1.1330x; 1.1330x over previous
//
#include <hip/hip_runtime.h>

// FeatureSelfAttention: B=32, T=2048, F=64
// out[b,t,i]    = x[b,t,i] + gamma[i] * mixed[b,t,i]
// attn[b,t,i,j] = softmax_j( q_i * k_j / 8 ),  q = x Wq^T, k = x Wk^T.
//
// R8 = R7 with the cvt_pkrtz type mismatch fixed (bit-cast __fp16x2 ->
// _Float16x2). Structure: each wave owns 16 CONSECUTIVE positions and reads
// its whole X slice (4 KB) into LDS in one coalesced burst at wave start.
// After the ~3 us chip-wide prologue the kernel issues ONLY stores.
// Theory: the 4.87-vs-6.5 TB/s gap (R2 vs fillBuffer) is HBM read/write
// turnaround mixing from 64k scattered 256 B X-reads sprinkled through the
// 1.07 GB write stream. Evidence: R6-B added ~5x more interleaved reads and
// dropped to 2.9 TB/s; nt stores (R4), dense fill-like sweep (R6), and
// store pipelining (R5) all failed -> not L2, not address pattern, not duty.
//
// Pass 1: lane i owns row i (lane-local sum/mix, no reductions).
// Pass 2: coalesced attn write, 4 rows x 16 lanes, contiguous 1 KB float4
// wave-stores; exp2 recomputed with {qs, log2(inv)} broadcast from LDS.
// No max-subtraction: |qs*k| <= ~1.9 provably, softmax shift-invariant.

#define LOG2E 1.4426950408889634f

constexpr int F = 64;

typedef _Float16 h2v __attribute__((ext_vector_type(2)));

#if defined(__has_builtin)
#if __has_builtin(__builtin_amdgcn_fdot2)
#define HAVE_FDOT2 1
#endif
#if __has_builtin(__builtin_amdgcn_cvt_pkrtz)
#define HAVE_PKRTZ 1
#endif
#endif

static __device__ __forceinline__ float fdot2(h2v a, h2v b, float c) {
#ifdef HAVE_FDOT2
    return __builtin_amdgcn_fdot2(a, b, c, false);
#else
    return c + (float)a[0] * (float)b[0] + (float)a[1] * (float)b[1];
#endif
}

static __device__ __forceinline__ h2v pk16(float x, float y) {
#ifdef HAVE_PKRTZ
    const auto r = __builtin_amdgcn_cvt_pkrtz(x, y);   // __fp16 x2
    h2v out;
    __builtin_memcpy(&out, &r, sizeof(out));           // same bits
    return out;
#else
    h2v r; r[0] = (_Float16)x; r[1] = (_Float16)y; return r;
#endif
}

__global__ __launch_bounds__(256, 4)
void fsattn(const float* __restrict__ X,
            const float* __restrict__ Wq,
            const float* __restrict__ Wk,
            const float* __restrict__ gamma,
            float* __restrict__ out,
            float* __restrict__ attn,
            int BT)
{
    const int lane = threadIdx.x & 63;
    const int wid  = threadIdx.x >> 6;          // wave within block (0..3)
    const int gw   = (blockIdx.x << 2) + wid;   // global wave id

    // per-wave scratch; no cross-wave sharing -> wave_barriers only
    __shared__ float  xb_lds[4][16][F];         // 16 positions of x (4 KB/wave)
    __shared__ float  k_lds [4][F];
    __shared__ float2 ql_lds[4][F];             // {qs, log2(inv)} per row

    // lane i holds row i of Wq/Wk as packed f16 pairs: 32+32 VGPRs
    h2v wq2[32], wk2[32];
#pragma unroll
    for (int p = 0; p < 32; ++p) {
        const float2 a = reinterpret_cast<const float2*>(Wq + lane * F)[p];
        const float2 b = reinterpret_cast<const float2*>(Wk + lane * F)[p];
        wq2[p] = pk16(a.x, a.y);
        wk2[p] = pk16(b.x, b.y);
    }
    const float g   = gamma[lane];
    const int   sub = lane >> 4;
    const int   c16 = lane & 15;

    const int t0 = gw * 16;                      // batch of 16 consecutive t
    if (t0 >= BT) return;
    const int np = min(16, BT - t0);

    // ---- prologue: the wave's ENTIRE global read, one 4 KB coalesced burst
    {
        const float4* Xb = reinterpret_cast<const float4*>(X + (size_t)t0 * F);
        float4*       xw = reinterpret_cast<float4*>(&xb_lds[wid][0][0]);
#pragma unroll
        for (int r = 0; r < 4; ++r)
            xw[lane + r * 64] = Xb[lane + r * 64];   // 1 KB per r, conflict-free
    }
    __builtin_amdgcn_wave_barrier();

    // ---- main: 16 positions, zero global reads, pure store stream
    for (int p16 = 0; p16 < np; ++p16) {
        const int t = t0 + p16;
        const float* xp = &xb_lds[wid][p16][0];
        const float  xv = xp[lane];

        // q_i, k_i matvec: f16 dot2; x pairs broadcast from LDS, packed inline
        float q = 0.f, k = 0.f;
#pragma unroll
        for (int p = 0; p < 32; ++p) {
            const float2 x2 = reinterpret_cast<const float2*>(xp)[p];
            const h2v    xh = pk16(x2.x, x2.y);
            q = fdot2(wq2[p], xh, q);
            k = fdot2(wk2[p], xh, k);
        }
        const float qs = q * (0.125f * LOG2E);   // log2-domain scaled q
        k_lds[wid][lane] = k;
        __builtin_amdgcn_wave_barrier();

        // pass 1: per-lane row sum + mixed accumulation (no reductions)
        float sum0 = 0.f, sum1 = 0.f, mix0 = 0.f, mix1 = 0.f;
#pragma unroll
        for (int j = 0; j < 16; ++j) {
            const float4 k4 = reinterpret_cast<const float4*>(k_lds[wid])[j];
            const float4 x4 = reinterpret_cast<const float4*>(xp)[j];
            const float e0 = __builtin_amdgcn_exp2f(qs * k4.x);
            const float e1 = __builtin_amdgcn_exp2f(qs * k4.y);
            const float e2 = __builtin_amdgcn_exp2f(qs * k4.z);
            const float e3 = __builtin_amdgcn_exp2f(qs * k4.w);
            sum0 += e0 + e1;
            sum1 += e2 + e3;
            mix0 = __builtin_fmaf(e0, x4.x, __builtin_fmaf(e1, x4.y, mix0));
            mix1 = __builtin_fmaf(e2, x4.z, __builtin_fmaf(e3, x4.w, mix1));
        }
        const float sum = sum0 + sum1;
        const float inv = __builtin_amdgcn_rcpf(sum);
        const float li  = -__builtin_amdgcn_logf(sum);   // log2(1/sum)
        float2 ql; ql.x = qs; ql.y = li;
        ql_lds[wid][lane] = ql;
        __builtin_amdgcn_wave_barrier();

        out[(size_t)t * F + lane] = xv + g * ((mix0 + mix1) * inv);

        // pass 2: coalesced attn write. 64 lanes cover 4 rows x 16 float4
        // (one contiguous 1 KB segment per store). inv folded into exponent.
        float* ap = attn + (size_t)t * (F * F);
        const float4 kc = reinterpret_cast<const float4*>(k_lds[wid])[c16];
#pragma unroll
        for (int i0 = 0; i0 < F; i0 += 4) {
            const int row = i0 + sub;
            const float2 qr = ql_lds[wid][row];     // broadcast ds_read_b64
            float4 w;
            w.x = __builtin_amdgcn_exp2f(__builtin_fmaf(qr.x, kc.x, qr.y));
            w.y = __builtin_amdgcn_exp2f(__builtin_fmaf(qr.x, kc.y, qr.y));
            w.z = __builtin_amdgcn_exp2f(__builtin_fmaf(qr.x, kc.z, qr.y));
            w.w = __builtin_amdgcn_exp2f(__builtin_fmaf(qr.x, kc.w, qr.y));
            reinterpret_cast<float4*>(ap + (size_t)row * F)[c16] = w;
        }
        __builtin_amdgcn_wave_barrier();   // k_lds/ql_lds reused next position
    }
}

extern "C" void kernel_launch(void* const* d_in, const int* in_sizes, int n_in,
                              void* d_out, int out_size, void* d_ws, size_t ws_size,
                              hipStream_t stream) {
    const float* X     = (const float*)d_in[0];
    const float* Wq    = (const float*)d_in[1];
    const float* Wk    = (const float*)d_in[2];
    const float* gamma = (const float*)d_in[3];

    const int BT = in_sizes[0] / F;              // 65536 positions
    float* out  = (float*)d_out;                 // (B,T,F) first
    float* attn = out + (size_t)BT * F;          // then (B,T,F,F)

    // 4096 waves x 16 consecutive positions = 65536
    const int nwaves = (BT + 15) / 16;
    const int nblk   = (nwaves + 3) / 4;
    hipLaunchKernelGGL(fsattn, dim3(nblk), dim3(256), 0, stream,
                       X, Wq, Wk, gamma, out, attn, BT);
}